// Round 3
// baseline (473.756 us; speedup 1.0000x reference)
//
#include <hip/hip_runtime.h>
#include <hip/hip_bf16.h>
#include <math.h>

// Problem constants (from reference setup_inputs)
constexpr int B     = 64;      // batch
constexpr int C     = 512;     // query input dim
constexpr int D     = 128;     // key/value dim
constexpr int NKEYS = 200000;  // memory size
constexpr int K     = 8;       // top_k

// kernel-2 decomposition: 512 blocks x 8 waves.
// Each block covers 4 key-ranges x 2 batch-halves.
// wave wv: range slot = wv>>1, batch half = wv&1.
// Within a wave: lane&1 = which half of D, lane>>1 = batch within half (32).
constexpr int NBLK2  = 512;
constexpr int RPB    = 4;                              // ranges per block
constexpr int NRANGE = NBLK2 * RPB;                    // 2048
constexpr int PERW   = (NKEYS + NRANGE - 1) / NRANGE;  // 98 keys per range

// ---------------------------------------------------------------------------
// top-8 register insertion (static indices after unroll)
__device__ __forceinline__ void topk_insert(float (&tv)[K], int (&ti)[K], float s, int n) {
    if (s <= tv[K - 1]) return;
    tv[K - 1] = s; ti[K - 1] = n;
#pragma unroll
    for (int j = K - 1; j > 0; --j) {
        if (tv[j] > tv[j - 1]) {
            float t = tv[j]; tv[j] = tv[j - 1]; tv[j - 1] = t;
            int   u = ti[j]; ti[j] = ti[j - 1]; ti[j - 1] = u;
        }
    }
}

// ---------------------------------------------------------------------------
// Kernel 1: q = query @ Wq + bq ; qn = l2norm(q) ; store transposed qt[d][b]
__global__ __launch_bounds__(256)
void k1_qproj(const float* __restrict__ query, const float* __restrict__ Wq,
              const float* __restrict__ bq, float* __restrict__ qt) {
    const int b = blockIdx.x;
    const int t = threadIdx.x;
    const int d = t & 127;
    const int h = t >> 7;                       // 0 or 1: which half of C
    const float* qr = query + (size_t)b * C;    // wave-uniform row

    float acc = 0.0f;
    const int c0 = h * (C / 2);
#pragma unroll 8
    for (int c = 0; c < C / 2; ++c)
        acc = fmaf(qr[c0 + c], Wq[(size_t)(c0 + c) * D + d], acc);

    __shared__ float part[2][D];
    part[h][d] = acc;
    __syncthreads();
    if (h == 0) {
        const float a = part[0][d] + part[1][d] + bq[d];
        float ss = a * a;
#pragma unroll
        for (int off = 32; off > 0; off >>= 1) ss += __shfl_xor(ss, off);
        __shared__ float w[2];
        if ((d & 63) == 0) w[d >> 6] = ss;
        __syncthreads();
        const float inv = 1.0f / fmaxf(sqrtf(w[0] + w[1]), 1e-12f);
        qt[(size_t)d * B + b] = a * inv;
    }
}

// ---------------------------------------------------------------------------
// Kernel 2: sim = (qn . k) * invnorm(k) * imp ; fused top-8.
// Lane pair shares a batch: each lane holds 64 q-floats (its D-half) in VGPRs.
__global__ __launch_bounds__(512, 2)
void k2_sim_topk(const float* __restrict__ keys, const float* __restrict__ imp,
                 const float* __restrict__ qt,
                 float* __restrict__ cval, int* __restrict__ cidx) {
    const int lane  = threadIdx.x & 63;
    const int wv    = __builtin_amdgcn_readfirstlane(threadIdx.x >> 6);
    const int rslot = wv >> 1;            // 0..3  (range slot)
    const int bhalf = wv & 1;             // 0/1   (batch half)
    const int range = blockIdx.x * RPB + rslot;
    const int kbeg  = range * PERW;
    const int kend  = min(kbeg + PERW, NKEYS);

    __shared__ float invn[RPB][PERW + 2];
    __shared__ float sval[8][32][K];
    __shared__ int   sidx[8][32][K];

    // ---- phase 1: key inverse norms; wave pair splits its range ----
    {
        const int half = lane >> 5, l32 = lane & 31;
        const int hlen = (PERW + 1) >> 1;            // 49
        const int nb   = kbeg + bhalf * hlen;
        const int ne   = min(nb + hlen, kend);
        for (int base = nb; base < ne; base += 2) {
            const int n = base + half;
            float ss = 0.0f;
            if (n < ne) {
                const float4 v = reinterpret_cast<const float4*>(keys + (size_t)n * D)[l32];
                ss = v.x * v.x + v.y * v.y + v.z * v.z + v.w * v.w;
            }
#pragma unroll
            for (int off = 16; off > 0; off >>= 1) ss += __shfl_xor(ss, off);
            if (l32 == 0 && n < ne)
                invn[rslot][n - kbeg] = 1.0f / fmaxf(sqrtf(ss), 1e-12f);
        }
    }
    __syncthreads();

    // ---- my batch + my D-half of the normalized q row -> 64 VGPRs ----
    const int b     = bhalf * 32 + (lane >> 1);
    const int dbase = (lane & 1) * 64;
    float q[64];
#pragma unroll
    for (int j = 0; j < 64; ++j) q[j] = qt[(size_t)(dbase + j) * B + b];

    // ---- phase 2: half-dots (4 keys in flight), pair-combine, top-8 ----
    float tv[K]; int ti[K];
#pragma unroll
    for (int j = 0; j < K; ++j) { tv[j] = -INFINITY; ti[j] = 0; }

    const int foff = (lane & 1) * 16;   // float4 offset of my D-half

    for (int n0 = kbeg; n0 < kend; n0 += 4) {
        const int n1 = min(n0 + 1, NKEYS - 1);
        const int n2 = min(n0 + 2, NKEYS - 1);
        const int n3 = min(n0 + 3, NKEYS - 1);
        const float4* __restrict__ kp0 = reinterpret_cast<const float4*>(keys + (size_t)n0 * D) + foff;
        const float4* __restrict__ kp1 = reinterpret_cast<const float4*>(keys + (size_t)n1 * D) + foff;
        const float4* __restrict__ kp2 = reinterpret_cast<const float4*>(keys + (size_t)n2 * D) + foff;
        const float4* __restrict__ kp3 = reinterpret_cast<const float4*>(keys + (size_t)n3 * D) + foff;
        float a0 = 0.f, a1 = 0.f, a2 = 0.f, a3 = 0.f;
#pragma unroll
        for (int c = 0; c < 16; ++c) {               // 64 elems per lane, static idx
            const float4 v0 = kp0[c];
            const float4 v1 = kp1[c];
            const float4 v2 = kp2[c];
            const float4 v3 = kp3[c];
            a0 = fmaf(q[4*c], v0.x, fmaf(q[4*c+1], v0.y, fmaf(q[4*c+2], v0.z, fmaf(q[4*c+3], v0.w, a0))));
            a1 = fmaf(q[4*c], v1.x, fmaf(q[4*c+1], v1.y, fmaf(q[4*c+2], v1.z, fmaf(q[4*c+3], v1.w, a1))));
            a2 = fmaf(q[4*c], v2.x, fmaf(q[4*c+1], v2.y, fmaf(q[4*c+2], v2.z, fmaf(q[4*c+3], v2.w, a2))));
            a3 = fmaf(q[4*c], v3.x, fmaf(q[4*c+1], v3.y, fmaf(q[4*c+2], v3.z, fmaf(q[4*c+3], v3.w, a3))));
        }
        // combine D-halves across the lane pair (exact: same adds both lanes)
        a0 += __shfl_xor(a0, 1);
        a1 += __shfl_xor(a1, 1);
        a2 += __shfl_xor(a2, 1);
        a3 += __shfl_xor(a3, 1);

        const float s0 = a0 * invn[rslot][n0 - kbeg] * imp[n0];
        const float s1 = a1 * invn[rslot][n1 - kbeg] * imp[n1];
        const float s2 = a2 * invn[rslot][n2 - kbeg] * imp[n2];
        const float s3 = a3 * invn[rslot][n3 - kbeg] * imp[n3];
        topk_insert(tv, ti, s0, n0);
        if (n0 + 1 < kend) topk_insert(tv, ti, s1, n0 + 1);
        if (n0 + 2 < kend) topk_insert(tv, ti, s2, n0 + 2);
        if (n0 + 3 < kend) topk_insert(tv, ti, s3, n0 + 3);
    }

    // ---- stash per-wave top-8 (even lane of each pair) ----
    if ((lane & 1) == 0) {
        const int lb = lane >> 1;
#pragma unroll
        for (int j = 0; j < K; ++j) { sval[wv][lb][j] = tv[j]; sidx[wv][lb][j] = ti[j]; }
    }
    __syncthreads();

    // ---- in-block merge: 4 ranges -> top-8 per batch; layout [b][block][8] ----
    if (threadIdx.x < B) {
        const int bb = threadIdx.x;
        const int bh = bb >> 5, lb = bb & 31;
        float mv[K]; int mi[K];
#pragma unroll
        for (int j = 0; j < K; ++j) { mv[j] = sval[bh][lb][j]; mi[j] = sidx[bh][lb][j]; }
#pragma unroll
        for (int r = 1; r < RPB; ++r) {
            const int w = 2 * r + bh;
#pragma unroll
            for (int j = 0; j < K; ++j)
                topk_insert(mv, mi, sval[w][lb][j], sidx[w][lb][j]);
        }
        const size_t base = ((size_t)bb * NBLK2 + blockIdx.x) * K;
#pragma unroll
        for (int j = 0; j < K; ++j) { cval[base + j] = mv[j]; cidx[base + j] = mi[j]; }
    }
}

// ---------------------------------------------------------------------------
// Kernel 3: merge 512 blocks' candidates -> global top-8 per batch
__global__ __launch_bounds__(64)
void k3_merge(const float* __restrict__ cval, const int* __restrict__ cidx,
              int* __restrict__ topidx) {
    const int b    = blockIdx.x;
    const int lane = threadIdx.x;  // 0..63
    constexpr int NC = NBLK2 * K;  // 4096 candidates per batch (contiguous)

    __shared__ float sv[64 * (K + 1)];
    __shared__ int   si[64 * (K + 1)];

    float tv[K]; int ti[K];
#pragma unroll
    for (int j = 0; j < K; ++j) { tv[j] = -INFINITY; ti[j] = 0; }

    const size_t rowbase = (size_t)b * NC;
    for (int i = 0; i < NC / 64; ++i) {
        const size_t a = rowbase + lane + 64 * i;   // coalesced
        const float v = cval[a];
        if (v > tv[K - 1]) topk_insert(tv, ti, v, cidx[a]);
    }
#pragma unroll
    for (int j = 0; j < K; ++j) {
        sv[lane * (K + 1) + j] = tv[j];
        si[lane * (K + 1) + j] = ti[j];
    }
    __syncthreads();

    for (int r = 0; r < K; ++r) {
        float best = -INFINITY; int bp = lane * (K + 1);
#pragma unroll
        for (int j = 0; j < K; ++j) {
            const float v = sv[lane * (K + 1) + j];
            if (v > best) { best = v; bp = lane * (K + 1) + j; }
        }
#pragma unroll
        for (int off = 32; off > 0; off >>= 1) {
            const float ov = __shfl_xor(best, off);
            const int   op = __shfl_xor(bp, off);
            if (ov > best || (ov == best && op < bp)) { best = ov; bp = op; }
        }
        if (lane == 0) {
            topidx[b * K + r] = si[bp];
            sv[bp] = -INFINITY;
        }
        __syncthreads();
    }
}

// ---------------------------------------------------------------------------
// Kernel 4: gather values, softmax attention, output projection
__global__ __launch_bounds__(128)
void k4_attend(const float* __restrict__ values, const int* __restrict__ topidx,
               const float* __restrict__ Wa, const float* __restrict__ ba,
               const float* __restrict__ Wc, const float* __restrict__ bc,
               float* __restrict__ out) {
    const int b = blockIdx.x;
    const int d = threadIdx.x;  // 0..127

    __shared__ float part[2][K];
    __shared__ float scores[K];
    __shared__ float comb[D];

    int idx[K];
#pragma unroll
    for (int k = 0; k < K; ++k) idx[k] = topidx[b * K + k];
    float v[K];
#pragma unroll
    for (int k = 0; k < K; ++k) v[k] = values[(size_t)idx[k] * D + d];

    const float wa = Wa[d];
    const int wvv = d >> 6;
#pragma unroll
    for (int k = 0; k < K; ++k) {
        float p = v[k] * wa;
#pragma unroll
        for (int off = 32; off > 0; off >>= 1) p += __shfl_xor(p, off);
        if ((d & 63) == 0) part[wvv][k] = p;
    }
    __syncthreads();
    if (d == 0) {
        float lg[K]; float mx = -INFINITY;
#pragma unroll
        for (int k = 0; k < K; ++k) { lg[k] = part[0][k] + part[1][k] + ba[0]; mx = fmaxf(mx, lg[k]); }
        float sum = 0.0f;
#pragma unroll
        for (int k = 0; k < K; ++k) { lg[k] = expf(lg[k] - mx); sum += lg[k]; }
        const float rs = 1.0f / sum;
#pragma unroll
        for (int k = 0; k < K; ++k) scores[k] = lg[k] * rs;
    }
    __syncthreads();

    float c = 0.0f;
#pragma unroll
    for (int k = 0; k < K; ++k) c = fmaf(scores[k], v[k], c);
    comb[d] = c;
    __syncthreads();

    float acc = bc[d];
    for (int dd = 0; dd < D; ++dd) acc = fmaf(comb[dd], Wc[(size_t)dd * D + d], acc);
    out[(size_t)b * D + d] = acc;
}

// ---------------------------------------------------------------------------
extern "C" void kernel_launch(void* const* d_in, const int* in_sizes, int n_in,
                              void* d_out, int out_size, void* d_ws, size_t ws_size,
                              hipStream_t stream) {
    const float* query = (const float*)d_in[0];   // [64,512]
    const float* keys  = (const float*)d_in[1];   // [200000,128]
    const float* vals  = (const float*)d_in[2];   // [200000,128]
    const float* imp   = (const float*)d_in[3];   // [200000]
    const float* Wq    = (const float*)d_in[4];   // [512,128]
    const float* bq    = (const float*)d_in[5];   // [128]
    const float* Wa    = (const float*)d_in[6];   // [128]
    const float* ba    = (const float*)d_in[7];   // [1]
    const float* Wc    = (const float*)d_in[8];   // [128,128]
    const float* bc    = (const float*)d_in[9];   // [128]
    // d_in[10] = top_k (always 8 per setup)

    float* out = (float*)d_out;

    // workspace layout (floats): ~2.13 MB (same footprint as proven rounds)
    float* qt     = (float*)d_ws;                 // 128*64
    float* cval   = qt + (size_t)D * B;           // 64*512*8  [b][block][8]
    int*   cidx   = (int*)(cval + (size_t)B * NBLK2 * K);
    int*   topidx = cidx + (size_t)B * NBLK2 * K; // 64*8

    k1_qproj<<<B, 256, 0, stream>>>(query, Wq, bq, qt);
    k2_sim_topk<<<NBLK2, 512, 0, stream>>>(keys, imp, qt, cval, cidx);
    k3_merge<<<B, 64, 0, stream>>>(cval, cidx, topidx);
    k4_attend<<<B, D, 0, stream>>>(vals, topidx, Wa, ba, Wc, bc, out);
}

// Round 4
// 163.623 us; speedup vs baseline: 2.8954x; 2.8954x over previous
//
#include <hip/hip_runtime.h>
#include <hip/hip_bf16.h>
#include <math.h>

// Problem constants
constexpr int B     = 64;      // batch
constexpr int C     = 512;     // query input dim
constexpr int D     = 128;     // key/value dim
constexpr int NKEYS = 200000;  // memory size
constexpr int K     = 8;       // top_k

// k2 decomposition: tiles of 64 keys, grid-strided over 3125 tiles
constexpr int KT     = 64;                 // keys per tile
constexpr int NTILES = NKEYS / KT;         // 3125 (exact)
constexpr int NBLK2  = 640;                // ~2.5 blocks/CU
constexpr int M32    = 32;                 // rescore candidate count

typedef __attribute__((ext_vector_type(8))) short bf16x8;
typedef __attribute__((ext_vector_type(4))) float f32x4;

// ---------------------------------------------------------------------------
template<int KK>
__device__ __forceinline__ void topk_ins(float (&tv)[KK], int (&ti)[KK], float s, int n) {
    if (s <= tv[KK - 1]) return;
    tv[KK - 1] = s; ti[KK - 1] = n;
#pragma unroll
    for (int j = KK - 1; j > 0; --j) {
        if (tv[j] > tv[j - 1]) {
            float t = tv[j]; tv[j] = tv[j - 1]; tv[j - 1] = t;
            int   u = ti[j]; ti[j] = ti[j - 1]; ti[j - 1] = u;
        }
    }
}

__device__ __forceinline__ short f2bf(float x) {
    __hip_bfloat16 h = __float2bfloat16(x);
    return __builtin_bit_cast(short, h);
}

// ---------------------------------------------------------------------------
// Kernel 1: q = query @ Wq + bq ; qn = l2norm(q) ; qt[d][b] fp32 + qbfT[b][d] bf16
__global__ __launch_bounds__(256)
void k1_qproj(const float* __restrict__ query, const float* __restrict__ Wq,
              const float* __restrict__ bq, float* __restrict__ qt,
              short* __restrict__ qbfT) {
    const int b = blockIdx.x;
    const int t = threadIdx.x;
    const int d = t & 127;
    const int h = t >> 7;
    const float* qr = query + (size_t)b * C;

    float acc = 0.0f;
    const int c0 = h * (C / 2);
#pragma unroll 8
    for (int c = 0; c < C / 2; ++c)
        acc = fmaf(qr[c0 + c], Wq[(size_t)(c0 + c) * D + d], acc);

    __shared__ float part[2][D];
    part[h][d] = acc;
    __syncthreads();
    if (h == 0) {
        const float a = part[0][d] + part[1][d] + bq[d];
        float ss = a * a;
#pragma unroll
        for (int off = 32; off > 0; off >>= 1) ss += __shfl_xor(ss, off);
        __shared__ float w[2];
        if ((d & 63) == 0) w[d >> 6] = ss;
        __syncthreads();
        const float inv = 1.0f / fmaxf(sqrtf(w[0] + w[1]), 1e-12f);
        const float qn = a * inv;
        qt[(size_t)d * B + b] = qn;
        qbfT[(size_t)b * D + d] = f2bf(qn);
    }
}

// ---------------------------------------------------------------------------
// Kernel 2: bf16 MFMA candidate scoring.
// C = keys(M) x batches(N): per tile of 64 keys, 16 C-tiles of 16x16, 8 waves.
// wave w: batch N-tile nb=w&3, key M-tiles {2*(w>>2), 2*(w>>2)+1}.
// LDS key tile XOR-swizzled (T2) for conflict-free ds_read_b128 A-frags.
__global__ __launch_bounds__(512, 2)
void k2_sim_topk(const float* __restrict__ keys, const float* __restrict__ imp,
                 const short* __restrict__ qbfT,
                 float* __restrict__ cval, int* __restrict__ cidx) {
    const int t    = threadIdx.x;
    const int lane = t & 63;
    const int w    = __builtin_amdgcn_readfirstlane(t >> 6);  // 0..7
    const int nb   = w & 3;
    const int wm   = w >> 2;

    __shared__ short klds[KT * 128];   // 16 KB, 256B rows, 16B-XOR swizzled
    __shared__ float scales[KT];
    __shared__ float mvs[2][B][K];
    __shared__ int   mis[2][B][K];

    // ---- q B-fragments (held for whole kernel): batch col = lane&15 ----
    bf16x8 bq[4];
    {
        const int batch  = nb * 16 + (lane & 15);
        const char* qrow = (const char*)(qbfT + (size_t)batch * D);
        const int coff   = (lane >> 4) * 16;
#pragma unroll
        for (int ks = 0; ks < 4; ++ks)
            bq[ks] = *(const bf16x8*)(qrow + ks * 64 + coff);
    }

    float tv[K]; int ti[K];
#pragma unroll
    for (int j = 0; j < K; ++j) { tv[j] = -INFINITY; ti[j] = 0; }

    const int r  = t >> 3;   // staged key row 0..63 (8 threads per row)
    const int c8 = t & 7;    // 16-float chunk within row
    const int sw = (r & 7) << 4;

    for (int tile = blockIdx.x; tile < NTILES; tile += NBLK2) {
        const int gk = tile * KT + r;    // global key this thread stages
        // ---- stage: 16 floats of key row -> ss partial + bf16 pack ----
        const float4* src = (const float4*)(keys + (size_t)gk * D + c8 * 16);
        float4 f0 = src[0], f1 = src[1], f2 = src[2], f3 = src[3];
        float ss = f0.x*f0.x + f0.y*f0.y + f0.z*f0.z + f0.w*f0.w
                 + f1.x*f1.x + f1.y*f1.y + f1.z*f1.z + f1.w*f1.w
                 + f2.x*f2.x + f2.y*f2.y + f2.z*f2.z + f2.w*f2.w
                 + f3.x*f3.x + f3.y*f3.y + f3.z*f3.z + f3.w*f3.w;
        ss += __shfl_xor(ss, 1);
        ss += __shfl_xor(ss, 2);
        ss += __shfl_xor(ss, 4);
        float sc = 0.0f;
        if (c8 == 0) sc = imp[gk] / fmaxf(sqrtf(ss), 1e-12f);

        bf16x8 p0, p1;
        p0[0]=f2bf(f0.x); p0[1]=f2bf(f0.y); p0[2]=f2bf(f0.z); p0[3]=f2bf(f0.w);
        p0[4]=f2bf(f1.x); p0[5]=f2bf(f1.y); p0[6]=f2bf(f1.z); p0[7]=f2bf(f1.w);
        p1[0]=f2bf(f2.x); p1[1]=f2bf(f2.y); p1[2]=f2bf(f2.z); p1[3]=f2bf(f2.w);
        p1[4]=f2bf(f3.x); p1[5]=f2bf(f3.y); p1[6]=f2bf(f3.z); p1[7]=f2bf(f3.w);

        __syncthreads();   // previous tile's MFMA reads complete
        *(bf16x8*)((char*)klds + r * 256 + ((c8 * 32     ) ^ sw)) = p0;
        *(bf16x8*)((char*)klds + r * 256 + ((c8 * 32 + 16) ^ sw)) = p1;
        if (c8 == 0) scales[r] = sc;
        __syncthreads();   // tile staged

        // ---- MFMA: 2 C-tiles per wave, 4 K-steps each ----
#pragma unroll
        for (int mi = 0; mi < 2; ++mi) {
            const int mk   = wm * 2 + mi;
            const int krow = mk * 16 + (lane & 15);
            const int swk  = (krow & 7) << 4;
            const char* arow = (const char*)klds + krow * 256;
            const int coff = (lane >> 4) * 16;
            f32x4 acc = {0.f, 0.f, 0.f, 0.f};
#pragma unroll
            for (int ks = 0; ks < 4; ++ks) {
                bf16x8 af = *(const bf16x8*)(arow + ((ks * 64 + coff) ^ swk));
                acc = __builtin_amdgcn_mfma_f32_16x16x32_bf16(af, bq[ks], acc, 0, 0, 0);
            }
            const int kl0 = mk * 16 + (lane >> 4) * 4;
#pragma unroll
            for (int j = 0; j < 4; ++j) {
                const int lk = kl0 + j;
                topk_ins<K>(tv, ti, acc[j] * scales[lk], tile * KT + lk);
            }
        }
    }

    // ---- in-wave butterfly merge across the 4 lane-groups (same batch) ----
#pragma unroll
    for (int off = 16; off <= 32; off <<= 1) {
        float ov[K]; int oi[K];
#pragma unroll
        for (int j = 0; j < K; ++j) { ov[j] = __shfl_xor(tv[j], off); oi[j] = __shfl_xor(ti[j], off); }
#pragma unroll
        for (int j = 0; j < K; ++j) topk_ins<K>(tv, ti, ov[j], oi[j]);
    }
    if (lane < 16) {
        const int bb = nb * 16 + lane;
#pragma unroll
        for (int j = 0; j < K; ++j) { mvs[wm][bb][j] = tv[j]; mis[wm][bb][j] = ti[j]; }
    }
    __syncthreads();

    // ---- cross-wave final merge, write candidates [b][block][8] ----
    if (t < B) {
        float fv[K]; int fi[K];
#pragma unroll
        for (int j = 0; j < K; ++j) { fv[j] = mvs[0][t][j]; fi[j] = mis[0][t][j]; }
#pragma unroll
        for (int j = 0; j < K; ++j) topk_ins<K>(fv, fi, mvs[1][t][j], mis[1][t][j]);
        const size_t base = ((size_t)t * NBLK2 + blockIdx.x) * K;
#pragma unroll
        for (int j = 0; j < K; ++j) { cval[base + j] = fv[j]; cidx[base + j] = fi[j]; }
    }
}

// ---------------------------------------------------------------------------
// Kernel 3: merge 640x8 bf16-scored candidates -> top-32 per batch
__global__ __launch_bounds__(64)
void k3_merge(const float* __restrict__ cval, const int* __restrict__ cidx,
              int* __restrict__ top32) {
    const int b = blockIdx.x, lane = threadIdx.x;
    constexpr int NC = NBLK2 * K;  // 5120

    float tv[16]; int ti[16];
#pragma unroll
    for (int j = 0; j < 16; ++j) { tv[j] = -INFINITY; ti[j] = 0; }
    const size_t base = (size_t)b * NC;
    for (int i = lane; i < NC; i += 64) {
        const float v = cval[base + i];
        if (v > tv[15]) topk_ins<16>(tv, ti, v, cidx[base + i]);
    }
    __shared__ float sv[64 * 17];
    __shared__ int   si[64 * 17];
#pragma unroll
    for (int j = 0; j < 16; ++j) { sv[lane * 17 + j] = tv[j]; si[lane * 17 + j] = ti[j]; }
    __syncthreads();

    int p = 0;
    for (int r = 0; r < M32; ++r) {
        float best = (p < 16) ? sv[lane * 17 + p] : -INFINITY;
        int bl = lane;
#pragma unroll
        for (int off = 32; off > 0; off >>= 1) {
            const float ov = __shfl_xor(best, off);
            const int   ol = __shfl_xor(bl, off);
            if (ov > best || (ov == best && ol < bl)) { best = ov; bl = ol; }
        }
        const int wp  = __shfl(p, bl);
        const int idx = si[bl * 17 + wp];
        if (lane == 0) top32[b * M32 + r] = idx;
        if (lane == bl) ++p;
    }
}

// ---------------------------------------------------------------------------
// Kernel 4: exact fp32 rescore of 32 candidates -> top-8 set -> attention -> Wc
__global__ __launch_bounds__(128)
void k4_attend(const float* __restrict__ keys, const float* __restrict__ values,
               const float* __restrict__ imp, const float* __restrict__ qt,
               const int* __restrict__ top32,
               const float* __restrict__ Wa, const float* __restrict__ ba,
               const float* __restrict__ Wc, const float* __restrict__ bc,
               float* __restrict__ out) {
    const int b = blockIdx.x;
    const int t = threadIdx.x;     // 0..127
    const int lane = t & 63, wv = t >> 6;

    __shared__ float qs[D];
    __shared__ float simл[M32];
    __shared__ int   idxl[M32];
    __shared__ int   sel[K];
    __shared__ float part[2][K];
    __shared__ float scores[K];
    __shared__ float comb[D];

    qs[t] = qt[(size_t)t * B + b];
    __syncthreads();

    // ---- fp32 rescore: wave wv handles candidates wv*16 .. wv*16+15 ----
    for (int ci = 0; ci < 16; ++ci) {
        const int r   = wv * 16 + ci;
        const int idx = top32[b * M32 + r];
        const float2 kv = ((const float2*)(keys + (size_t)idx * D))[lane];
        float dot = kv.x * qs[2 * lane] + kv.y * qs[2 * lane + 1];
        float ss  = kv.x * kv.x + kv.y * kv.y;
#pragma unroll
        for (int off = 32; off > 0; off >>= 1) {
            dot += __shfl_xor(dot, off);
            ss  += __shfl_xor(ss, off);
        }
        if (lane == 0) {
            simл[r] = dot * (1.0f / fmaxf(sqrtf(ss), 1e-12f)) * imp[idx];
            idxl[r] = idx;
        }
    }
    __syncthreads();

    // ---- exact top-8 set of the 32 (order irrelevant downstream) ----
    if (t == 0) {
        float fv[K]; int fi[K];
#pragma unroll
        for (int j = 0; j < K; ++j) { fv[j] = -INFINITY; fi[j] = 0; }
        for (int r = 0; r < M32; ++r) topk_ins<K>(fv, fi, simл[r], idxl[r]);
#pragma unroll
        for (int j = 0; j < K; ++j) sel[j] = fi[j];
    }
    __syncthreads();

    // ---- attention over the 8 retrieved values + output projection ----
    float v[K];
#pragma unroll
    for (int k = 0; k < K; ++k) v[k] = values[(size_t)sel[k] * D + t];

    const float wa = Wa[t];
#pragma unroll
    for (int k = 0; k < K; ++k) {
        float p = v[k] * wa;
#pragma unroll
        for (int off = 32; off > 0; off >>= 1) p += __shfl_xor(p, off);
        if ((t & 63) == 0) part[wv][k] = p;
    }
    __syncthreads();
    if (t == 0) {
        float lg[K]; float mx = -INFINITY;
#pragma unroll
        for (int k = 0; k < K; ++k) { lg[k] = part[0][k] + part[1][k] + ba[0]; mx = fmaxf(mx, lg[k]); }
        float sum = 0.0f;
#pragma unroll
        for (int k = 0; k < K; ++k) { lg[k] = expf(lg[k] - mx); sum += lg[k]; }
        const float rs = 1.0f / sum;
#pragma unroll
        for (int k = 0; k < K; ++k) scores[k] = lg[k] * rs;
    }
    __syncthreads();

    float c = 0.0f;
#pragma unroll
    for (int k = 0; k < K; ++k) c = fmaf(scores[k], v[k], c);
    comb[t] = c;
    __syncthreads();

    float acc = bc[t];
    for (int dd = 0; dd < D; ++dd) acc = fmaf(comb[dd], Wc[(size_t)dd * D + t], acc);
    out[(size_t)b * D + t] = acc;
}

// ---------------------------------------------------------------------------
extern "C" void kernel_launch(void* const* d_in, const int* in_sizes, int n_in,
                              void* d_out, int out_size, void* d_ws, size_t ws_size,
                              hipStream_t stream) {
    const float* query = (const float*)d_in[0];
    const float* keys  = (const float*)d_in[1];
    const float* vals  = (const float*)d_in[2];
    const float* imp   = (const float*)d_in[3];
    const float* Wq    = (const float*)d_in[4];
    const float* bq    = (const float*)d_in[5];
    const float* Wa    = (const float*)d_in[6];
    const float* ba    = (const float*)d_in[7];
    const float* Wc    = (const float*)d_in[8];
    const float* bc    = (const float*)d_in[9];

    float* out = (float*)d_out;

    // workspace layout: qt 32KB | qbfT 16KB | cval 1.31MB | cidx 1.31MB | top32
    float* qt    = (float*)d_ws;                         // 128*64 f32
    short* qbfT  = (short*)(qt + (size_t)D * B);         // 64*128 bf16
    float* cval  = (float*)(qbfT + (size_t)B * D);       // 64*640*8 f32
    int*   cidx  = (int*)(cval + (size_t)B * NBLK2 * K); // 64*640*8 i32
    int*   top32 = cidx + (size_t)B * NBLK2 * K;         // 64*32 i32

    k1_qproj<<<B, 256, 0, stream>>>(query, Wq, bq, qt, qbfT);
    k2_sim_topk<<<NBLK2, 512, 0, stream>>>(keys, imp, qbfT, cval, cidx);
    k3_merge<<<B, 64, 0, stream>>>(cval, cidx, top32);
    k4_attend<<<B, 128, 0, stream>>>(keys, vals, imp, qt, top32, Wa, ba, Wc, bc, out);
}

// Round 5
// 143.141 us; speedup vs baseline: 3.3097x; 1.1431x over previous
//
#include <hip/hip_runtime.h>
#include <hip/hip_bf16.h>
#include <math.h>

// Problem constants
constexpr int B     = 64;      // batch
constexpr int C     = 512;     // query input dim
constexpr int D     = 128;     // key/value dim
constexpr int NKEYS = 200000;  // memory size
constexpr int K     = 8;       // top_k

// k2 decomposition: tiles of 64 keys, grid-strided over 3125 tiles
constexpr int KT     = 64;                 // keys per tile
constexpr int NTILES = NKEYS / KT;         // 3125 (exact)
constexpr int NBLK2  = 640;                // ~2.5 blocks/CU
constexpr int NCAND  = 64;                 // rescore candidates per batch (4 waves x 16)

typedef __attribute__((ext_vector_type(8))) short bf16x8;
typedef __attribute__((ext_vector_type(4))) float f32x4;

// ---------------------------------------------------------------------------
template<int KK>
__device__ __forceinline__ void topk_ins(float (&tv)[KK], int (&ti)[KK], float s, int n) {
    if (s <= tv[KK - 1]) return;
    tv[KK - 1] = s; ti[KK - 1] = n;
#pragma unroll
    for (int j = KK - 1; j > 0; --j) {
        if (tv[j] > tv[j - 1]) {
            float t = tv[j]; tv[j] = tv[j - 1]; tv[j - 1] = t;
            int   u = ti[j]; ti[j] = ti[j - 1]; ti[j - 1] = u;
        }
    }
}

__device__ __forceinline__ short f2bf(float x) {
    __hip_bfloat16 h = __float2bfloat16(x);
    return __builtin_bit_cast(short, h);
}

// ---------------------------------------------------------------------------
// Kernel 1: q = query @ Wq + bq ; qn = l2norm(q) ; qt[d][b] fp32 + qbfT[b][d] bf16
__global__ __launch_bounds__(256)
void k1_qproj(const float* __restrict__ query, const float* __restrict__ Wq,
              const float* __restrict__ bq, float* __restrict__ qt,
              short* __restrict__ qbfT) {
    const int b = blockIdx.x;
    const int t = threadIdx.x;
    const int d = t & 127;
    const int h = t >> 7;
    const float* qr = query + (size_t)b * C;

    float acc = 0.0f;
    const int c0 = h * (C / 2);
#pragma unroll 8
    for (int c = 0; c < C / 2; ++c)
        acc = fmaf(qr[c0 + c], Wq[(size_t)(c0 + c) * D + d], acc);

    __shared__ float part[2][D];
    part[h][d] = acc;
    __syncthreads();
    if (h == 0) {
        const float a = part[0][d] + part[1][d] + bq[d];
        float ss = a * a;
#pragma unroll
        for (int off = 32; off > 0; off >>= 1) ss += __shfl_xor(ss, off);
        __shared__ float w[2];
        if ((d & 63) == 0) w[d >> 6] = ss;
        __syncthreads();
        const float inv = 1.0f / fmaxf(sqrtf(w[0] + w[1]), 1e-12f);
        const float qn = a * inv;
        qt[(size_t)d * B + b] = qn;
        qbfT[(size_t)b * D + d] = f2bf(qn);
    }
}

// ---------------------------------------------------------------------------
// Kernel 2: bf16 MFMA candidate scoring (unchanged from round 4).
__global__ __launch_bounds__(512, 2)
void k2_sim_topk(const float* __restrict__ keys, const float* __restrict__ imp,
                 const short* __restrict__ qbfT,
                 float* __restrict__ cval, int* __restrict__ cidx) {
    const int t    = threadIdx.x;
    const int lane = t & 63;
    const int w    = __builtin_amdgcn_readfirstlane(t >> 6);  // 0..7
    const int nb   = w & 3;
    const int wm   = w >> 2;

    __shared__ short klds[KT * 128];   // 16 KB, 256B rows, 16B-XOR swizzled
    __shared__ float scales[KT];
    __shared__ float mvs[2][B][K];
    __shared__ int   mis[2][B][K];

    // ---- q B-fragments (held for whole kernel): batch col = lane&15 ----
    bf16x8 bq[4];
    {
        const int batch  = nb * 16 + (lane & 15);
        const char* qrow = (const char*)(qbfT + (size_t)batch * D);
        const int coff   = (lane >> 4) * 16;
#pragma unroll
        for (int ks = 0; ks < 4; ++ks)
            bq[ks] = *(const bf16x8*)(qrow + ks * 64 + coff);
    }

    float tv[K]; int ti[K];
#pragma unroll
    for (int j = 0; j < K; ++j) { tv[j] = -INFINITY; ti[j] = 0; }

    const int r  = t >> 3;   // staged key row 0..63 (8 threads per row)
    const int c8 = t & 7;    // 16-float chunk within row
    const int sw = (r & 7) << 4;

    for (int tile = blockIdx.x; tile < NTILES; tile += NBLK2) {
        const int gk = tile * KT + r;    // global key this thread stages
        const float4* src = (const float4*)(keys + (size_t)gk * D + c8 * 16);
        float4 f0 = src[0], f1 = src[1], f2 = src[2], f3 = src[3];
        float ss = f0.x*f0.x + f0.y*f0.y + f0.z*f0.z + f0.w*f0.w
                 + f1.x*f1.x + f1.y*f1.y + f1.z*f1.z + f1.w*f1.w
                 + f2.x*f2.x + f2.y*f2.y + f2.z*f2.z + f2.w*f2.w
                 + f3.x*f3.x + f3.y*f3.y + f3.z*f3.z + f3.w*f3.w;
        ss += __shfl_xor(ss, 1);
        ss += __shfl_xor(ss, 2);
        ss += __shfl_xor(ss, 4);
        float sc = 0.0f;
        if (c8 == 0) sc = imp[gk] / fmaxf(sqrtf(ss), 1e-12f);

        bf16x8 p0, p1;
        p0[0]=f2bf(f0.x); p0[1]=f2bf(f0.y); p0[2]=f2bf(f0.z); p0[3]=f2bf(f0.w);
        p0[4]=f2bf(f1.x); p0[5]=f2bf(f1.y); p0[6]=f2bf(f1.z); p0[7]=f2bf(f1.w);
        p1[0]=f2bf(f2.x); p1[1]=f2bf(f2.y); p1[2]=f2bf(f2.z); p1[3]=f2bf(f2.w);
        p1[4]=f2bf(f3.x); p1[5]=f2bf(f3.y); p1[6]=f2bf(f3.z); p1[7]=f2bf(f3.w);

        __syncthreads();   // previous tile's MFMA reads complete
        *(bf16x8*)((char*)klds + r * 256 + ((c8 * 32     ) ^ sw)) = p0;
        *(bf16x8*)((char*)klds + r * 256 + ((c8 * 32 + 16) ^ sw)) = p1;
        if (c8 == 0) scales[r] = sc;
        __syncthreads();   // tile staged

        // ---- MFMA: 2 C-tiles per wave, 4 K-steps each ----
#pragma unroll
        for (int mi = 0; mi < 2; ++mi) {
            const int mk   = wm * 2 + mi;
            const int krow = mk * 16 + (lane & 15);
            const int swk  = (krow & 7) << 4;
            const char* arow = (const char*)klds + krow * 256;
            const int coff = (lane >> 4) * 16;
            f32x4 acc = {0.f, 0.f, 0.f, 0.f};
#pragma unroll
            for (int ks = 0; ks < 4; ++ks) {
                bf16x8 af = *(const bf16x8*)(arow + ((ks * 64 + coff) ^ swk));
                acc = __builtin_amdgcn_mfma_f32_16x16x32_bf16(af, bq[ks], acc, 0, 0, 0);
            }
            const int kl0 = mk * 16 + (lane >> 4) * 4;
#pragma unroll
            for (int j = 0; j < 4; ++j) {
                const int lk = kl0 + j;
                topk_ins<K>(tv, ti, acc[j] * scales[lk], tile * KT + lk);
            }
        }
    }

    // ---- in-wave butterfly merge across the 4 lane-groups (same batch) ----
#pragma unroll
    for (int off = 16; off <= 32; off <<= 1) {
        float ov[K]; int oi[K];
#pragma unroll
        for (int j = 0; j < K; ++j) { ov[j] = __shfl_xor(tv[j], off); oi[j] = __shfl_xor(ti[j], off); }
#pragma unroll
        for (int j = 0; j < K; ++j) topk_ins<K>(tv, ti, ov[j], oi[j]);
    }
    if (lane < 16) {
        const int bb = nb * 16 + lane;
#pragma unroll
        for (int j = 0; j < K; ++j) { mvs[wm][bb][j] = tv[j]; mis[wm][bb][j] = ti[j]; }
    }
    __syncthreads();

    // ---- cross-wave final merge, write candidates [b][block][8] ----
    if (t < B) {
        float fv[K]; int fi[K];
#pragma unroll
        for (int j = 0; j < K; ++j) { fv[j] = mvs[0][t][j]; fi[j] = mis[0][t][j]; }
#pragma unroll
        for (int j = 0; j < K; ++j) topk_ins<K>(fv, fi, mvs[1][t][j], mis[1][t][j]);
        const size_t base = ((size_t)t * NBLK2 + blockIdx.x) * K;
#pragma unroll
        for (int j = 0; j < K; ++j) { cval[base + j] = fv[j]; cidx[base + j] = fi[j]; }
    }
}

// ---------------------------------------------------------------------------
// Kernel 3: union-of-partitions candidate reduce.
// 256 threads/batch. Lane: top-16 of its 20 entries (4-deep load batches).
// Wave: 6-stage butterfly -> wave top-16. Output: 4 waves x 16 = 64 indices.
// Guarantee: any key top-16 within its partition cell survives => union
// contains the global bf16 top-16 (more than the prior top-32 safety margin).
__global__ __launch_bounds__(256)
void k3_merge(const float* __restrict__ cval, const int* __restrict__ cidx,
              int* __restrict__ cand) {
    const int b = blockIdx.x, t = threadIdx.x;
    const int lane = t & 63, w = t >> 6;
    constexpr int NC  = NBLK2 * K;    // 5120 candidates per batch
    constexpr int PER = NC / 256;     // 20 per thread

    float tv[16]; int ti[16];
#pragma unroll
    for (int j = 0; j < 16; ++j) { tv[j] = -INFINITY; ti[j] = 0; }

    const size_t base = (size_t)b * NC + t;
#pragma unroll
    for (int it = 0; it < PER; it += 4) {
        const float v0 = cval[base + (it + 0) * 256];
        const float v1 = cval[base + (it + 1) * 256];
        const float v2 = cval[base + (it + 2) * 256];
        const float v3 = cval[base + (it + 3) * 256];
        const int   i0 = cidx[base + (it + 0) * 256];
        const int   i1 = cidx[base + (it + 1) * 256];
        const int   i2 = cidx[base + (it + 2) * 256];
        const int   i3 = cidx[base + (it + 3) * 256];
        topk_ins<16>(tv, ti, v0, i0);
        topk_ins<16>(tv, ti, v1, i1);
        topk_ins<16>(tv, ti, v2, i2);
        topk_ins<16>(tv, ti, v3, i3);
    }

    // butterfly: all 64 lanes converge to the wave's top-16
#pragma unroll
    for (int off = 1; off <= 32; off <<= 1) {
        float ov[16]; int oi[16];
#pragma unroll
        for (int j = 0; j < 16; ++j) {
            ov[j] = __shfl_xor(tv[j], off);
            oi[j] = __shfl_xor(ti[j], off);
        }
#pragma unroll
        for (int j = 0; j < 16; ++j) topk_ins<16>(tv, ti, ov[j], oi[j]);
    }

    if (lane == 0) {
#pragma unroll
        for (int j = 0; j < 16; ++j) cand[b * NCAND + w * 16 + j] = ti[j];
    }
}

// ---------------------------------------------------------------------------
// Kernel 4: exact fp32 rescore of 64 candidates -> top-8 set -> attention -> Wc
// 256 threads: 4 waves rescore 16 candidates each; attention uses t<128.
__global__ __launch_bounds__(256)
void k4_attend(const float* __restrict__ keys, const float* __restrict__ values,
               const float* __restrict__ imp, const float* __restrict__ qt,
               const int* __restrict__ cand,
               const float* __restrict__ Wa, const float* __restrict__ ba,
               const float* __restrict__ Wc, const float* __restrict__ bc,
               float* __restrict__ out) {
    const int b = blockIdx.x;
    const int t = threadIdx.x;     // 0..255
    const int lane = t & 63, w = t >> 6;

    __shared__ float qs[D];
    __shared__ float simL[NCAND];
    __shared__ int   idxL[NCAND];
    __shared__ int   sel[K];
    __shared__ float part[2][K];
    __shared__ float scores[K];
    __shared__ float comb[D];

    if (t < D) qs[t] = qt[(size_t)t * B + b];
    __syncthreads();

    // ---- fp32 rescore: wave w handles candidates w*16 .. w*16+15 ----
    for (int ci = 0; ci < 16; ++ci) {
        const int r   = w * 16 + ci;
        const int idx = cand[b * NCAND + r];
        const float2 kv = ((const float2*)(keys + (size_t)idx * D))[lane];
        float dot = kv.x * qs[2 * lane] + kv.y * qs[2 * lane + 1];
        float ss  = kv.x * kv.x + kv.y * kv.y;
#pragma unroll
        for (int off = 32; off > 0; off >>= 1) {
            dot += __shfl_xor(dot, off);
            ss  += __shfl_xor(ss, off);
        }
        if (lane == 0) {
            simL[r] = dot * (1.0f / fmaxf(sqrtf(ss), 1e-12f)) * imp[idx];
            idxL[r] = idx;
        }
    }
    __syncthreads();

    // ---- exact top-8 set of the 64 (order irrelevant downstream) ----
    if (t == 0) {
        float fv[K]; int fi[K];
#pragma unroll
        for (int j = 0; j < K; ++j) { fv[j] = -INFINITY; fi[j] = 0; }
        for (int r = 0; r < NCAND; ++r) topk_ins<K>(fv, fi, simL[r], idxL[r]);
#pragma unroll
        for (int j = 0; j < K; ++j) sel[j] = fi[j];
    }
    __syncthreads();

    // ---- attention over the 8 retrieved values + output projection ----
    const int d = t & 127;
    float v[K];
#pragma unroll
    for (int k = 0; k < K; ++k) v[k] = values[(size_t)sel[k] * D + d];

    const float wa = Wa[d];
#pragma unroll
    for (int k = 0; k < K; ++k) {
        float p = v[k] * wa;
#pragma unroll
        for (int off = 32; off > 0; off >>= 1) p += __shfl_xor(p, off);
        if (t < 128 && (t & 63) == 0) part[t >> 6][k] = p;
    }
    __syncthreads();
    if (t == 0) {
        float lg[K]; float mx = -INFINITY;
#pragma unroll
        for (int k = 0; k < K; ++k) { lg[k] = part[0][k] + part[1][k] + ba[0]; mx = fmaxf(mx, lg[k]); }
        float sum = 0.0f;
#pragma unroll
        for (int k = 0; k < K; ++k) { lg[k] = expf(lg[k] - mx); sum += lg[k]; }
        const float rs = 1.0f / sum;
#pragma unroll
        for (int k = 0; k < K; ++k) scores[k] = lg[k] * rs;
    }
    __syncthreads();

    if (t < 128) {
        float c = 0.0f;
#pragma unroll
        for (int k = 0; k < K; ++k) c = fmaf(scores[k], v[k], c);
        comb[t] = c;
    }
    __syncthreads();

    if (t < 128) {
        float acc = bc[t];
        for (int dd = 0; dd < D; ++dd) acc = fmaf(comb[dd], Wc[(size_t)dd * D + t], acc);
        out[(size_t)b * D + t] = acc;
    }
}

// ---------------------------------------------------------------------------
extern "C" void kernel_launch(void* const* d_in, const int* in_sizes, int n_in,
                              void* d_out, int out_size, void* d_ws, size_t ws_size,
                              hipStream_t stream) {
    const float* query = (const float*)d_in[0];
    const float* keys  = (const float*)d_in[1];
    const float* vals  = (const float*)d_in[2];
    const float* imp   = (const float*)d_in[3];
    const float* Wq    = (const float*)d_in[4];
    const float* bq    = (const float*)d_in[5];
    const float* Wa    = (const float*)d_in[6];
    const float* ba    = (const float*)d_in[7];
    const float* Wc    = (const float*)d_in[8];
    const float* bc    = (const float*)d_in[9];

    float* out = (float*)d_out;

    // workspace: qt 32KB | qbfT 16KB | cval 1.31MB | cidx 1.31MB | cand 16KB
    float* qt   = (float*)d_ws;                          // 128*64 f32
    short* qbfT = (short*)(qt + (size_t)D * B);          // 64*128 bf16
    float* cval = (float*)(qbfT + (size_t)B * D);        // 64*640*8 f32
    int*   cidx = (int*)(cval + (size_t)B * NBLK2 * K);  // 64*640*8 i32
    int*   cand = cidx + (size_t)B * NBLK2 * K;          // 64*64 i32

    k1_qproj<<<B, 256, 0, stream>>>(query, Wq, bq, qt, qbfT);
    k2_sim_topk<<<NBLK2, 512, 0, stream>>>(keys, imp, qbfT, cval, cidx);
    k3_merge<<<B, 256, 0, stream>>>(cval, cidx, cand);
    k4_attend<<<B, 256, 0, stream>>>(keys, vals, imp, qt, cand, Wa, ba, Wc, bc, out);
}

// Round 6
// 127.478 us; speedup vs baseline: 3.7164x; 1.1229x over previous
//
#include <hip/hip_runtime.h>
#include <hip/hip_bf16.h>
#include <math.h>

// Problem constants
constexpr int B     = 64;      // batch
constexpr int C     = 512;     // query input dim
constexpr int D     = 128;     // key/value dim
constexpr int NKEYS = 200000;  // memory size
constexpr int K     = 8;       // top_k

// k2 decomposition
constexpr int KT     = 64;                 // keys per tile
constexpr int NTILES = NKEYS / KT;         // 3125 (exact)
constexpr int NBLK2  = 512;                // exactly 2 blocks/CU
constexpr int NCAND  = 64;                 // rescore candidates per batch

typedef __attribute__((ext_vector_type(8))) short bf16x8;
typedef __attribute__((ext_vector_type(4))) float f32x4;
typedef unsigned int uint32;

// ---------------------------------------------------------------------------
template<int KK>
__device__ __forceinline__ void topk_ins(float (&tv)[KK], int (&ti)[KK], float s, int n) {
    if (s <= tv[KK - 1]) return;
    tv[KK - 1] = s; ti[KK - 1] = n;
#pragma unroll
    for (int j = KK - 1; j > 0; --j) {
        if (tv[j] > tv[j - 1]) {
            float t = tv[j]; tv[j] = tv[j - 1]; tv[j - 1] = t;
            int   u = ti[j]; ti[j] = ti[j - 1]; ti[j - 1] = u;
        }
    }
}

__device__ __forceinline__ short f2bf(float x) {
    __hip_bfloat16 h = __float2bfloat16(x);
    return __builtin_bit_cast(short, h);
}

// pack 4 f32 -> 4 bf16 (round-half-up) in 2 u32 via v_perm_b32
__device__ __forceinline__ void pack_bf4(const float4& f, uint32& lo, uint32& hi) {
    const uint32 a0 = __builtin_bit_cast(uint32, f.x) + 0x8000u;
    const uint32 a1 = __builtin_bit_cast(uint32, f.y) + 0x8000u;
    const uint32 a2 = __builtin_bit_cast(uint32, f.z) + 0x8000u;
    const uint32 a3 = __builtin_bit_cast(uint32, f.w) + 0x8000u;
    lo = __builtin_amdgcn_perm(a1, a0, 0x07060302u);  // [bf(y)|bf(x)]
    hi = __builtin_amdgcn_perm(a3, a2, 0x07060302u);  // [bf(w)|bf(z)]
}

// ---------------------------------------------------------------------------
// Kernel 1: q = query @ Wq + bq ; qn = l2norm(q) ; qt[d][b] fp32 + qbfT[b][d] bf16
__global__ __launch_bounds__(256)
void k1_qproj(const float* __restrict__ query, const float* __restrict__ Wq,
              const float* __restrict__ bq, float* __restrict__ qt,
              short* __restrict__ qbfT) {
    const int b = blockIdx.x;
    const int t = threadIdx.x;
    const int d = t & 127;
    const int h = t >> 7;
    const float* qr = query + (size_t)b * C;

    float acc = 0.0f;
    const int c0 = h * (C / 2);
#pragma unroll 8
    for (int c = 0; c < C / 2; ++c)
        acc = fmaf(qr[c0 + c], Wq[(size_t)(c0 + c) * D + d], acc);

    __shared__ float part[2][D];
    part[h][d] = acc;
    __syncthreads();
    if (h == 0) {
        const float a = part[0][d] + part[1][d] + bq[d];
        float ss = a * a;
#pragma unroll
        for (int off = 32; off > 0; off >>= 1) ss += __shfl_xor(ss, off);
        __shared__ float w[2];
        if ((d & 63) == 0) w[d >> 6] = ss;
        __syncthreads();
        const float inv = 1.0f / fmaxf(sqrtf(w[0] + w[1]), 1e-12f);
        const float qn = a * inv;
        qt[(size_t)d * B + b] = qn;
        qbfT[(size_t)b * D + d] = f2bf(qn);
    }
}

// ---------------------------------------------------------------------------
// Kernel 2: bf16 MFMA candidate scoring, double-buffered pipeline.
// One raw s_barrier per tile (lgkmcnt only) so prefetch loads stay in
// flight across the barrier. Staging fully coalesced; write layout
// conflict-free; reads use the (row&7)<<4 XOR swizzle.
__global__ __launch_bounds__(512, 2)
void k2_sim_topk(const float* __restrict__ keys, const float* __restrict__ imp,
                 const short* __restrict__ qbfT,
                 float* __restrict__ cval, int* __restrict__ cidx) {
    const int t    = threadIdx.x;
    const int lane = t & 63;
    const int w    = __builtin_amdgcn_readfirstlane(t >> 6);  // 0..7
    const int nb   = w & 3;
    const int wm   = w >> 2;

    __shared__ short klds[2][KT * 128];   // 2 x 16 KB
    __shared__ float scales[2][KT];
    __shared__ float mvs[2][B][K];
    __shared__ int   mis[2][B][K];

    // ---- q B-fragments (held for whole kernel): batch col = lane&15 ----
    bf16x8 bq[4];
    {
        const int batch  = nb * 16 + (lane & 15);
        const char* qrow = (const char*)(qbfT + (size_t)batch * D);
        const int coff   = (lane >> 4) * 16;
#pragma unroll
        for (int ks = 0; ks < 4; ++ks)
            bq[ks] = *(const bf16x8*)(qrow + ks * 64 + coff);
    }

    float tv[K]; int ti[K];
#pragma unroll
    for (int j = 0; j < K; ++j) { tv[j] = -INFINITY; ti[j] = 0; }

    // staging geometry: instr i covers flat float4 [i*512 + t];
    // row_i = i*16 + hrow, col(float4) = hcol. Same swizzle for all i.
    const int hrow = t >> 5;        // 0..15
    const int hcol = t & 31;        // 0..31
    const int wbyte = hrow * 256 + ((hcol * 8) ^ ((hrow & 7) << 4));
    const bool writer = (hcol == 0);

    // ---- prologue: load tile0 + its imp ----
    int tile = blockIdx.x;
    float4 f0, f1, f2, f3;
    float impc[4];
    {
        const float4* tb = (const float4*)(keys + (size_t)tile * KT * D);
        f0 = tb[t]; f1 = tb[512 + t]; f2 = tb[1024 + t]; f3 = tb[1536 + t];
        if (writer) {
#pragma unroll
            for (int i = 0; i < 4; ++i) impc[i] = imp[tile * KT + i * 16 + hrow];
        }
    }

    int cur = 0;
    for (;;) {
        const int next = tile + NBLK2;
        const bool has_next = next < NTILES;

        // ---- ss partials + half-wave reduce (rows are per (i, hrow)) ----
        float s0 = f0.x*f0.x + f0.y*f0.y + f0.z*f0.z + f0.w*f0.w;
        float s1 = f1.x*f1.x + f1.y*f1.y + f1.z*f1.z + f1.w*f1.w;
        float s2 = f2.x*f2.x + f2.y*f2.y + f2.z*f2.z + f2.w*f2.w;
        float s3 = f3.x*f3.x + f3.y*f3.y + f3.z*f3.z + f3.w*f3.w;
#pragma unroll
        for (int off = 1; off < 32; off <<= 1) {
            s0 += __shfl_xor(s0, off);
            s1 += __shfl_xor(s1, off);
            s2 += __shfl_xor(s2, off);
            s3 += __shfl_xor(s3, off);
        }

        // ---- pack to bf16 (frees f-regs for the next loads) ----
        uint32 pk[8];
        pack_bf4(f0, pk[0], pk[1]);
        pack_bf4(f1, pk[2], pk[3]);
        pack_bf4(f2, pk[4], pk[5]);
        pack_bf4(f3, pk[6], pk[7]);

        // ---- issue next-tile loads (in flight across barrier + MFMA) ----
        if (has_next) {
            const float4* tb = (const float4*)(keys + (size_t)next * KT * D);
            f0 = tb[t]; f1 = tb[512 + t]; f2 = tb[1024 + t]; f3 = tb[1536 + t];
        }

        // ---- ds_write current tile (bank-clean 8B writes) ----
        char* kb = (char*)klds[cur];
        *(uint2*)(kb + wbyte        ) = make_uint2(pk[0], pk[1]);
        *(uint2*)(kb + wbyte +  4096) = make_uint2(pk[2], pk[3]);
        *(uint2*)(kb + wbyte +  8192) = make_uint2(pk[4], pk[5]);
        *(uint2*)(kb + wbyte + 12288) = make_uint2(pk[6], pk[7]);
        if (writer) {
            scales[cur][ 0 + hrow] = impc[0] / fmaxf(sqrtf(s0), 1e-12f);
            scales[cur][16 + hrow] = impc[1] / fmaxf(sqrtf(s1), 1e-12f);
            scales[cur][32 + hrow] = impc[2] / fmaxf(sqrtf(s2), 1e-12f);
            scales[cur][48 + hrow] = impc[3] / fmaxf(sqrtf(s3), 1e-12f);
        }
        if (has_next && writer) {
#pragma unroll
            for (int i = 0; i < 4; ++i) impc[i] = imp[next * KT + i * 16 + hrow];
        }

        // LDS writes visible; global prefetch NOT drained (raw barrier)
        asm volatile("s_waitcnt lgkmcnt(0)" ::: "memory");
        __builtin_amdgcn_s_barrier();
        asm volatile("" ::: "memory");

        // ---- MFMA: 2 C-tiles per wave, 4 K-steps each ----
#pragma unroll
        for (int mi = 0; mi < 2; ++mi) {
            const int mk   = wm * 2 + mi;
            const int krow = mk * 16 + (lane & 15);
            const int swk  = (krow & 7) << 4;
            const char* arow = (const char*)klds[cur] + krow * 256;
            const int coff = (lane >> 4) * 16;
            f32x4 acc = {0.f, 0.f, 0.f, 0.f};
#pragma unroll
            for (int ks = 0; ks < 4; ++ks) {
                bf16x8 af = *(const bf16x8*)(arow + ((ks * 64 + coff) ^ swk));
                acc = __builtin_amdgcn_mfma_f32_16x16x32_bf16(af, bq[ks], acc, 0, 0, 0);
            }
            const int kl0 = mk * 16 + (lane >> 4) * 4;
            const f32x4 scv = *(const f32x4*)&scales[cur][kl0];
#pragma unroll
            for (int j = 0; j < 4; ++j)
                topk_ins<K>(tv, ti, acc[j] * scv[j], tile * KT + kl0 + j);
        }

        if (!has_next) break;
        tile = next;
        cur ^= 1;
    }

    // ---- in-wave butterfly merge across the 4 lane-groups (same batch) ----
#pragma unroll
    for (int off = 16; off <= 32; off <<= 1) {
        float ov[K]; int oi[K];
#pragma unroll
        for (int j = 0; j < K; ++j) { ov[j] = __shfl_xor(tv[j], off); oi[j] = __shfl_xor(ti[j], off); }
#pragma unroll
        for (int j = 0; j < K; ++j) topk_ins<K>(tv, ti, ov[j], oi[j]);
    }
    if (lane < 16) {
        const int bb = nb * 16 + lane;
#pragma unroll
        for (int j = 0; j < K; ++j) { mvs[wm][bb][j] = tv[j]; mis[wm][bb][j] = ti[j]; }
    }
    __syncthreads();

    // ---- cross-wave final merge, write candidates [b][block][8] ----
    if (t < B) {
        float fv[K]; int fi[K];
#pragma unroll
        for (int j = 0; j < K; ++j) { fv[j] = mvs[0][t][j]; fi[j] = mis[0][t][j]; }
#pragma unroll
        for (int j = 0; j < K; ++j) topk_ins<K>(fv, fi, mvs[1][t][j], mis[1][t][j]);
        const size_t base = ((size_t)t * NBLK2 + blockIdx.x) * K;
#pragma unroll
        for (int j = 0; j < K; ++j) { cval[base + j] = fv[j]; cidx[base + j] = fi[j]; }
    }
}

// ---------------------------------------------------------------------------
// Kernel 3+4 fused: candidate union reduce -> exact fp32 rescore ->
// top-8 set -> softmax attention -> output projection. One block per batch.
__global__ __launch_bounds__(256)
void k34_select_attend(const float* __restrict__ cval, const int* __restrict__ cidx,
                       const float* __restrict__ keys, const float* __restrict__ values,
                       const float* __restrict__ imp, const float* __restrict__ qt,
                       const float* __restrict__ Wa, const float* __restrict__ ba,
                       const float* __restrict__ Wc, const float* __restrict__ bc,
                       float* __restrict__ out) {
    const int b = blockIdx.x;
    const int t = threadIdx.x;     // 0..255
    const int lane = t & 63, w = t >> 6;
    constexpr int NC  = NBLK2 * K;   // 4096 candidates per batch
    constexpr int PER = NC / 256;    // 16 per thread

    __shared__ int   candL[NCAND];
    __shared__ float qs[D];
    __shared__ float simL[NCAND];
    __shared__ int   sel[K];
    __shared__ float part[2][K];
    __shared__ float scores[K];
    __shared__ float comb[D];

    if (t < D) qs[t] = qt[(size_t)t * B + b];

    // ---- phase A: per-thread top-16 over 16 entries, wave butterfly ----
    float tv[16]; int ti[16];
#pragma unroll
    for (int j = 0; j < 16; ++j) { tv[j] = -INFINITY; ti[j] = 0; }

    const size_t base = (size_t)b * NC + t;
#pragma unroll
    for (int it = 0; it < PER; it += 4) {
        const float v0 = cval[base + (it + 0) * 256];
        const float v1 = cval[base + (it + 1) * 256];
        const float v2 = cval[base + (it + 2) * 256];
        const float v3 = cval[base + (it + 3) * 256];
        const int   i0 = cidx[base + (it + 0) * 256];
        const int   i1 = cidx[base + (it + 1) * 256];
        const int   i2 = cidx[base + (it + 2) * 256];
        const int   i3 = cidx[base + (it + 3) * 256];
        topk_ins<16>(tv, ti, v0, i0);
        topk_ins<16>(tv, ti, v1, i1);
        topk_ins<16>(tv, ti, v2, i2);
        topk_ins<16>(tv, ti, v3, i3);
    }
#pragma unroll
    for (int off = 1; off <= 32; off <<= 1) {
        float ov[16]; int oi[16];
#pragma unroll
        for (int j = 0; j < 16; ++j) {
            ov[j] = __shfl_xor(tv[j], off);
            oi[j] = __shfl_xor(ti[j], off);
        }
#pragma unroll
        for (int j = 0; j < 16; ++j) topk_ins<16>(tv, ti, ov[j], oi[j]);
    }
    if (lane == 0) {
#pragma unroll
        for (int j = 0; j < 16; ++j) candL[w * 16 + j] = ti[j];
    }
    __syncthreads();

    // ---- phase B: exact fp32 rescore of the 64-candidate union ----
    for (int ci = 0; ci < 16; ++ci) {
        const int r   = w * 16 + ci;
        const int idx = candL[r];
        const float2 kv = ((const float2*)(keys + (size_t)idx * D))[lane];
        float dot = kv.x * qs[2 * lane] + kv.y * qs[2 * lane + 1];
        float ss  = kv.x * kv.x + kv.y * kv.y;
#pragma unroll
        for (int off = 32; off > 0; off >>= 1) {
            dot += __shfl_xor(dot, off);
            ss  += __shfl_xor(ss, off);
        }
        if (lane == 0)
            simL[r] = dot * (1.0f / fmaxf(sqrtf(ss), 1e-12f)) * imp[idx];
    }
    __syncthreads();

    // ---- phase C: exact top-8 set (order irrelevant downstream) ----
    if (t == 0) {
        float fv[K]; int fi[K];
#pragma unroll
        for (int j = 0; j < K; ++j) { fv[j] = -INFINITY; fi[j] = 0; }
        for (int r = 0; r < NCAND; ++r) topk_ins<K>(fv, fi, simL[r], candL[r]);
#pragma unroll
        for (int j = 0; j < K; ++j) sel[j] = fi[j];
    }
    __syncthreads();

    // ---- attention over the 8 retrieved values + output projection ----
    const int d = t & 127;
    float v[K];
#pragma unroll
    for (int k = 0; k < K; ++k) v[k] = values[(size_t)sel[k] * D + d];

    const float wa = Wa[d];
#pragma unroll
    for (int k = 0; k < K; ++k) {
        float p = v[k] * wa;
#pragma unroll
        for (int off = 32; off > 0; off >>= 1) p += __shfl_xor(p, off);
        if (t < 128 && (t & 63) == 0) part[t >> 6][k] = p;
    }
    __syncthreads();
    if (t == 0) {
        float lg[K]; float mx = -INFINITY;
#pragma unroll
        for (int k = 0; k < K; ++k) { lg[k] = part[0][k] + part[1][k] + ba[0]; mx = fmaxf(mx, lg[k]); }
        float sum = 0.0f;
#pragma unroll
        for (int k = 0; k < K; ++k) { lg[k] = expf(lg[k] - mx); sum += lg[k]; }
        const float rs = 1.0f / sum;
#pragma unroll
        for (int k = 0; k < K; ++k) scores[k] = lg[k] * rs;
    }
    __syncthreads();

    if (t < 128) {
        float c = 0.0f;
#pragma unroll
        for (int k = 0; k < K; ++k) c = fmaf(scores[k], v[k], c);
        comb[t] = c;
    }
    __syncthreads();

    if (t < 128) {
        float acc = bc[t];
        for (int dd = 0; dd < D; ++dd) acc = fmaf(comb[dd], Wc[(size_t)dd * D + t], acc);
        out[(size_t)b * D + t] = acc;
    }
}

// ---------------------------------------------------------------------------
extern "C" void kernel_launch(void* const* d_in, const int* in_sizes, int n_in,
                              void* d_out, int out_size, void* d_ws, size_t ws_size,
                              hipStream_t stream) {
    const float* query = (const float*)d_in[0];
    const float* keys  = (const float*)d_in[1];
    const float* vals  = (const float*)d_in[2];
    const float* imp   = (const float*)d_in[3];
    const float* Wq    = (const float*)d_in[4];
    const float* bq    = (const float*)d_in[5];
    const float* Wa    = (const float*)d_in[6];
    const float* ba    = (const float*)d_in[7];
    const float* Wc    = (const float*)d_in[8];
    const float* bc    = (const float*)d_in[9];

    float* out = (float*)d_out;

    // workspace: qt 32KB | qbfT 16KB | cval 1MB | cidx 1MB  (~2.1 MB total)
    float* qt   = (float*)d_ws;                          // 128*64 f32
    short* qbfT = (short*)(qt + (size_t)D * B);          // 64*128 bf16
    float* cval = (float*)(qbfT + (size_t)B * D);        // 64*512*8 f32
    int*   cidx = (int*)(cval + (size_t)B * NBLK2 * K);  // 64*512*8 i32

    k1_qproj<<<B, 256, 0, stream>>>(query, Wq, bq, qt, qbfT);
    k2_sim_topk<<<NBLK2, 512, 0, stream>>>(keys, imp, qbfT, cval, cidx);
    k34_select_attend<<<B, 256, 0, stream>>>(cval, cidx, keys, vals, imp, qt,
                                             Wa, ba, Wc, bc, out);
}

// Round 7
// 78.019 us; speedup vs baseline: 6.0723x; 1.6339x over previous
//
#include <hip/hip_runtime.h>
#include <hip/hip_bf16.h>
#include <math.h>

// Problem constants
constexpr int B     = 64;      // batch
constexpr int C     = 512;     // query input dim
constexpr int D     = 128;     // key/value dim
constexpr int NKEYS = 200000;  // memory size
constexpr int K     = 8;       // top_k

// k2 decomposition
constexpr int KT     = 64;                 // keys per tile
constexpr int NTILES = NKEYS / KT;         // 3125 (exact)
constexpr int NBLK2  = 512;                // exactly 2 blocks/CU
constexpr int TOPSEL = 48;                 // rescore-threshold rank target
constexpr int CAP    = 512;                // max compacted candidates

typedef __attribute__((ext_vector_type(8))) short bf16x8;
typedef __attribute__((ext_vector_type(4))) float f32x4;
typedef unsigned int uint32;

// ---------------------------------------------------------------------------
template<int KK>
__device__ __forceinline__ void topk_ins(float (&tv)[KK], int (&ti)[KK], float s, int n) {
    if (s <= tv[KK - 1]) return;
    tv[KK - 1] = s; ti[KK - 1] = n;
#pragma unroll
    for (int j = KK - 1; j > 0; --j) {
        if (tv[j] > tv[j - 1]) {
            float t = tv[j]; tv[j] = tv[j - 1]; tv[j - 1] = t;
            int   u = ti[j]; ti[j] = ti[j - 1]; ti[j - 1] = u;
        }
    }
}

__device__ __forceinline__ short f2bf(float x) {
    __hip_bfloat16 h = __float2bfloat16(x);
    return __builtin_bit_cast(short, h);
}

// order-preserving float -> u32 key (ascending float == ascending unsigned)
__device__ __forceinline__ uint32 fkey(float f) {
    uint32 u = __builtin_bit_cast(uint32, f);
    return ((int)u < 0) ? ~u : (u | 0x80000000u);
}

// pack 4 f32 -> 4 bf16 (round-half-up) in 2 u32 via v_perm_b32
__device__ __forceinline__ void pack_bf4(const float4& f, uint32& lo, uint32& hi) {
    const uint32 a0 = __builtin_bit_cast(uint32, f.x) + 0x8000u;
    const uint32 a1 = __builtin_bit_cast(uint32, f.y) + 0x8000u;
    const uint32 a2 = __builtin_bit_cast(uint32, f.z) + 0x8000u;
    const uint32 a3 = __builtin_bit_cast(uint32, f.w) + 0x8000u;
    lo = __builtin_amdgcn_perm(a1, a0, 0x07060302u);
    hi = __builtin_amdgcn_perm(a3, a2, 0x07060302u);
}

// ---------------------------------------------------------------------------
// Kernel 1: q = query @ Wq + bq ; qn = l2norm(q) ; qt[d][b] fp32 + qbfT[b][d] bf16
__global__ __launch_bounds__(256)
void k1_qproj(const float* __restrict__ query, const float* __restrict__ Wq,
              const float* __restrict__ bq, float* __restrict__ qt,
              short* __restrict__ qbfT) {
    const int b = blockIdx.x;
    const int t = threadIdx.x;
    const int d = t & 127;
    const int h = t >> 7;
    const float* qr = query + (size_t)b * C;

    float acc = 0.0f;
    const int c0 = h * (C / 2);
#pragma unroll 8
    for (int c = 0; c < C / 2; ++c)
        acc = fmaf(qr[c0 + c], Wq[(size_t)(c0 + c) * D + d], acc);

    __shared__ float part[2][D];
    part[h][d] = acc;
    __syncthreads();
    if (h == 0) {
        const float a = part[0][d] + part[1][d] + bq[d];
        float ss = a * a;
#pragma unroll
        for (int off = 32; off > 0; off >>= 1) ss += __shfl_xor(ss, off);
        __shared__ float w[2];
        if ((d & 63) == 0) w[d >> 6] = ss;
        __syncthreads();
        const float inv = 1.0f / fmaxf(sqrtf(w[0] + w[1]), 1e-12f);
        const float qn = a * inv;
        qt[(size_t)d * B + b] = qn;
        qbfT[(size_t)b * D + d] = f2bf(qn);
    }
}

// ---------------------------------------------------------------------------
// Kernel 2: bf16 MFMA candidate scoring, double-buffered (unchanged round 6).
__global__ __launch_bounds__(512, 2)
void k2_sim_topk(const float* __restrict__ keys, const float* __restrict__ imp,
                 const short* __restrict__ qbfT,
                 float* __restrict__ cval, int* __restrict__ cidx) {
    const int t    = threadIdx.x;
    const int lane = t & 63;
    const int w    = __builtin_amdgcn_readfirstlane(t >> 6);  // 0..7
    const int nb   = w & 3;
    const int wm   = w >> 2;

    __shared__ short klds[2][KT * 128];   // 2 x 16 KB
    __shared__ float scales[2][KT];
    __shared__ float mvs[2][B][K];
    __shared__ int   mis[2][B][K];

    bf16x8 bq[4];
    {
        const int batch  = nb * 16 + (lane & 15);
        const char* qrow = (const char*)(qbfT + (size_t)batch * D);
        const int coff   = (lane >> 4) * 16;
#pragma unroll
        for (int ks = 0; ks < 4; ++ks)
            bq[ks] = *(const bf16x8*)(qrow + ks * 64 + coff);
    }

    float tv[K]; int ti[K];
#pragma unroll
    for (int j = 0; j < K; ++j) { tv[j] = -INFINITY; ti[j] = 0; }

    const int hrow = t >> 5;        // 0..15
    const int hcol = t & 31;        // 0..31
    const int wbyte = hrow * 256 + ((hcol * 8) ^ ((hrow & 7) << 4));
    const bool writer = (hcol == 0);

    int tile = blockIdx.x;
    float4 f0, f1, f2, f3;
    float impc[4];
    {
        const float4* tb = (const float4*)(keys + (size_t)tile * KT * D);
        f0 = tb[t]; f1 = tb[512 + t]; f2 = tb[1024 + t]; f3 = tb[1536 + t];
        if (writer) {
#pragma unroll
            for (int i = 0; i < 4; ++i) impc[i] = imp[tile * KT + i * 16 + hrow];
        }
    }

    int cur = 0;
    for (;;) {
        const int next = tile + NBLK2;
        const bool has_next = next < NTILES;

        float s0 = f0.x*f0.x + f0.y*f0.y + f0.z*f0.z + f0.w*f0.w;
        float s1 = f1.x*f1.x + f1.y*f1.y + f1.z*f1.z + f1.w*f1.w;
        float s2 = f2.x*f2.x + f2.y*f2.y + f2.z*f2.z + f2.w*f2.w;
        float s3 = f3.x*f3.x + f3.y*f3.y + f3.z*f3.z + f3.w*f3.w;
#pragma unroll
        for (int off = 1; off < 32; off <<= 1) {
            s0 += __shfl_xor(s0, off);
            s1 += __shfl_xor(s1, off);
            s2 += __shfl_xor(s2, off);
            s3 += __shfl_xor(s3, off);
        }

        uint32 pk[8];
        pack_bf4(f0, pk[0], pk[1]);
        pack_bf4(f1, pk[2], pk[3]);
        pack_bf4(f2, pk[4], pk[5]);
        pack_bf4(f3, pk[6], pk[7]);

        if (has_next) {
            const float4* tb = (const float4*)(keys + (size_t)next * KT * D);
            f0 = tb[t]; f1 = tb[512 + t]; f2 = tb[1024 + t]; f3 = tb[1536 + t];
        }

        char* kb = (char*)klds[cur];
        *(uint2*)(kb + wbyte        ) = make_uint2(pk[0], pk[1]);
        *(uint2*)(kb + wbyte +  4096) = make_uint2(pk[2], pk[3]);
        *(uint2*)(kb + wbyte +  8192) = make_uint2(pk[4], pk[5]);
        *(uint2*)(kb + wbyte + 12288) = make_uint2(pk[6], pk[7]);
        if (writer) {
            scales[cur][ 0 + hrow] = impc[0] / fmaxf(sqrtf(s0), 1e-12f);
            scales[cur][16 + hrow] = impc[1] / fmaxf(sqrtf(s1), 1e-12f);
            scales[cur][32 + hrow] = impc[2] / fmaxf(sqrtf(s2), 1e-12f);
            scales[cur][48 + hrow] = impc[3] / fmaxf(sqrtf(s3), 1e-12f);
        }
        if (has_next && writer) {
#pragma unroll
            for (int i = 0; i < 4; ++i) impc[i] = imp[next * KT + i * 16 + hrow];
        }

        asm volatile("s_waitcnt lgkmcnt(0)" ::: "memory");
        __builtin_amdgcn_s_barrier();
        asm volatile("" ::: "memory");

#pragma unroll
        for (int mi = 0; mi < 2; ++mi) {
            const int mk   = wm * 2 + mi;
            const int krow = mk * 16 + (lane & 15);
            const int swk  = (krow & 7) << 4;
            const char* arow = (const char*)klds[cur] + krow * 256;
            const int coff = (lane >> 4) * 16;
            f32x4 acc = {0.f, 0.f, 0.f, 0.f};
#pragma unroll
            for (int ks = 0; ks < 4; ++ks) {
                bf16x8 af = *(const bf16x8*)(arow + ((ks * 64 + coff) ^ swk));
                acc = __builtin_amdgcn_mfma_f32_16x16x32_bf16(af, bq[ks], acc, 0, 0, 0);
            }
            const int kl0 = mk * 16 + (lane >> 4) * 4;
            const f32x4 scv = *(const f32x4*)&scales[cur][kl0];
#pragma unroll
            for (int j = 0; j < 4; ++j)
                topk_ins<K>(tv, ti, acc[j] * scv[j], tile * KT + kl0 + j);
        }

        if (!has_next) break;
        tile = next;
        cur ^= 1;
    }

#pragma unroll
    for (int off = 16; off <= 32; off <<= 1) {
        float ov[K]; int oi[K];
#pragma unroll
        for (int j = 0; j < K; ++j) { ov[j] = __shfl_xor(tv[j], off); oi[j] = __shfl_xor(ti[j], off); }
#pragma unroll
        for (int j = 0; j < K; ++j) topk_ins<K>(tv, ti, ov[j], oi[j]);
    }
    if (lane < 16) {
        const int bb = nb * 16 + lane;
#pragma unroll
        for (int j = 0; j < K; ++j) { mvs[wm][bb][j] = tv[j]; mis[wm][bb][j] = ti[j]; }
    }
    __syncthreads();

    if (t < B) {
        float fv[K]; int fi[K];
#pragma unroll
        for (int j = 0; j < K; ++j) { fv[j] = mvs[0][t][j]; fi[j] = mis[0][t][j]; }
#pragma unroll
        for (int j = 0; j < K; ++j) topk_ins<K>(fv, fi, mvs[1][t][j], mis[1][t][j]);
        const size_t base = ((size_t)t * NBLK2 + blockIdx.x) * K;
#pragma unroll
        for (int j = 0; j < K; ++j) { cval[base + j] = fv[j]; cidx[base + j] = fi[j]; }
    }
}

// ---------------------------------------------------------------------------
// Kernel 3+4 fused: histogram-threshold candidate select -> exact fp32
// rescore -> top-8 set -> softmax attention -> output projection.
// One block (256 threads) per batch.
__global__ __launch_bounds__(256)
void k34_select_attend(const float* __restrict__ cval, const int* __restrict__ cidx,
                       const float* __restrict__ keys, const float* __restrict__ values,
                       const float* __restrict__ imp, const float* __restrict__ qt,
                       const float* __restrict__ Wa, const float* __restrict__ ba,
                       const float* __restrict__ Wc, const float* __restrict__ bc,
                       float* __restrict__ out) {
    const int b = blockIdx.x;
    const int t = threadIdx.x;     // 0..255
    const int lane = t & 63, w = t >> 6;
    constexpr int NC  = NBLK2 * K;   // 4096 candidates per batch
    constexpr int PER = NC / 256;    // 16 per thread

    __shared__ uint32 hist[4096];    // 12-bit-bin histogram (16 KB)
    __shared__ uint32 coarse[256];
    __shared__ int    candL[CAP];
    __shared__ float  simL[CAP];
    __shared__ float  qs[D];
    __shared__ int    thrBin_s, cnt_s, ncand_s;
    __shared__ int    sel[K];
    __shared__ float  part[2][K];
    __shared__ float  scores[K];
    __shared__ float  comb[D];

    // ---- init ----
#pragma unroll
    for (int i = 0; i < 16; ++i) hist[t + i * 256] = 0;
    if (t == 0) cnt_s = 0;
    if (t < D) qs[t] = qt[(size_t)t * B + b];
    __syncthreads();

    // ---- phase A: load candidates, histogram their ordered keys ----
    uint32 oks[PER]; int ids[PER];
    const size_t base = (size_t)b * NC + t;
#pragma unroll
    for (int i = 0; i < PER; ++i) {
        oks[i] = fkey(cval[base + i * 256]);
        ids[i] = cidx[base + i * 256];
    }
#pragma unroll
    for (int i = 0; i < PER; ++i)
        atomicAdd(&hist[oks[i] >> 20], 1u);
    __syncthreads();

    // ---- phase A2: two-level suffix scan -> threshold bin ----
    uint32 cs = 0;
#pragma unroll
    for (int j = 0; j < 16; ++j) cs += hist[t * 16 + j];
    coarse[t] = cs;
    __syncthreads();

    if (t < 64) {
        const uint32 g = coarse[4 * t] + coarse[4 * t + 1]
                       + coarse[4 * t + 2] + coarse[4 * t + 3];
        uint32 suf = g;
#pragma unroll
        for (int off = 1; off < 64; off <<= 1) {
            const uint32 o = __shfl_down(suf, off);
            if (t + off < 64) suf += o;
        }
        const uint32 sufnext = __shfl_down(suf, 1);
        const uint32 above0  = (t == 63) ? 0u : sufnext;
        if (suf >= TOPSEL && (t == 63 || sufnext < TOPSEL)) {
            // boundary lane: refine within my 4 coarse bins, then 16 fine bins
            uint32 above = above0;
            int c = 4 * t + 3;
            while (above + coarse[c] < TOPSEL) { above += coarse[c]; --c; }
            int fb = c * 16 + 15;
            while (above + hist[fb] < TOPSEL) { above += hist[fb]; --fb; }
            thrBin_s = fb;
        }
    }
    __syncthreads();
    const uint32 thrKey = (uint32)thrBin_s << 20;

    // ---- phase A3: threshold compaction ----
#pragma unroll
    for (int i = 0; i < PER; ++i) {
        if (oks[i] >= thrKey) {
            const int p = atomicAdd(&cnt_s, 1);
            if (p < CAP) candL[p] = ids[i];
        }
    }
    __syncthreads();
    if (t == 0) ncand_s = min(cnt_s, CAP);
    __syncthreads();
    const int ncand = ncand_s;

    // ---- phase B: exact fp32 rescore (8 candidates in flight per pass) ----
    const int sub = lane >> 5, l32 = lane & 31;
    for (int r = w * 2 + sub; r < ncand; r += 8) {
        const int idx = candL[r];
        const float4 kv = ((const float4*)(keys + (size_t)idx * D))[l32];
        float dot = kv.x * qs[4 * l32] + kv.y * qs[4 * l32 + 1]
                  + kv.z * qs[4 * l32 + 2] + kv.w * qs[4 * l32 + 3];
        float ss  = kv.x * kv.x + kv.y * kv.y + kv.z * kv.z + kv.w * kv.w;
#pragma unroll
        for (int off = 1; off < 32; off <<= 1) {
            dot += __shfl_xor(dot, off);
            ss  += __shfl_xor(ss, off);
        }
        if (l32 == 0)
            simL[r] = dot * (1.0f / fmaxf(sqrtf(ss), 1e-12f)) * imp[idx];
    }
    __syncthreads();

    // ---- phase C: top-8 set on wave 0 (8-deep lists only) ----
    if (t < 64) {
        float fv[K]; int fi[K];
#pragma unroll
        for (int j = 0; j < K; ++j) { fv[j] = -INFINITY; fi[j] = 0; }
        for (int r = t; r < ncand; r += 64) topk_ins<K>(fv, fi, simL[r], candL[r]);
#pragma unroll
        for (int off = 1; off <= 32; off <<= 1) {
            float ov[K]; int oi[K];
#pragma unroll
            for (int j = 0; j < K; ++j) { ov[j] = __shfl_xor(fv[j], off); oi[j] = __shfl_xor(fi[j], off); }
#pragma unroll
            for (int j = 0; j < K; ++j) topk_ins<K>(fv, fi, ov[j], oi[j]);
        }
        if (t == 0) {
#pragma unroll
            for (int j = 0; j < K; ++j) sel[j] = fi[j];
        }
    }
    __syncthreads();

    // ---- attention over the 8 retrieved values + output projection ----
    const int d = t & 127;
    float v[K];
#pragma unroll
    for (int k = 0; k < K; ++k) v[k] = values[(size_t)sel[k] * D + d];

    const float wa = Wa[d];
#pragma unroll
    for (int k = 0; k < K; ++k) {
        float p = v[k] * wa;
#pragma unroll
        for (int off = 32; off > 0; off >>= 1) p += __shfl_xor(p, off);
        if (t < 128 && (t & 63) == 0) part[t >> 6][k] = p;
    }
    __syncthreads();
    if (t == 0) {
        float lg[K]; float mx = -INFINITY;
#pragma unroll
        for (int k = 0; k < K; ++k) { lg[k] = part[0][k] + part[1][k] + ba[0]; mx = fmaxf(mx, lg[k]); }
        float sum = 0.0f;
#pragma unroll
        for (int k = 0; k < K; ++k) { lg[k] = expf(lg[k] - mx); sum += lg[k]; }
        const float rs = 1.0f / sum;
#pragma unroll
        for (int k = 0; k < K; ++k) scores[k] = lg[k] * rs;
    }
    __syncthreads();

    if (t < 128) {
        float c = 0.0f;
#pragma unroll
        for (int k = 0; k < K; ++k) c = fmaf(scores[k], v[k], c);
        comb[t] = c;
    }
    __syncthreads();

    if (t < 128) {
        float acc = bc[t];
        for (int dd = 0; dd < D; ++dd) acc = fmaf(comb[dd], Wc[(size_t)dd * D + t], acc);
        out[(size_t)b * D + t] = acc;
    }
}

// ---------------------------------------------------------------------------
extern "C" void kernel_launch(void* const* d_in, const int* in_sizes, int n_in,
                              void* d_out, int out_size, void* d_ws, size_t ws_size,
                              hipStream_t stream) {
    const float* query = (const float*)d_in[0];
    const float* keys  = (const float*)d_in[1];
    const float* vals  = (const float*)d_in[2];
    const float* imp   = (const float*)d_in[3];
    const float* Wq    = (const float*)d_in[4];
    const float* bq    = (const float*)d_in[5];
    const float* Wa    = (const float*)d_in[6];
    const float* ba    = (const float*)d_in[7];
    const float* Wc    = (const float*)d_in[8];
    const float* bc    = (const float*)d_in[9];

    float* out = (float*)d_out;

    // workspace: qt 32KB | qbfT 16KB | cval 1MB | cidx 1MB  (~2.1 MB total)
    float* qt   = (float*)d_ws;                          // 128*64 f32
    short* qbfT = (short*)(qt + (size_t)D * B);          // 64*128 bf16
    float* cval = (float*)(qbfT + (size_t)B * D);        // 64*512*8 f32
    int*   cidx = (int*)(cval + (size_t)B * NBLK2 * K);  // 64*512*8 i32

    k1_qproj<<<B, 256, 0, stream>>>(query, Wq, bq, qt, qbfT);
    k2_sim_topk<<<NBLK2, 512, 0, stream>>>(keys, imp, qbfT, cval, cidx);
    k34_select_attend<<<B, 256, 0, stream>>>(cval, cidx, keys, vals, imp, qt,
                                             Wa, ba, Wc, bc, out);
}